// Round 1
// baseline (1528.727 us; speedup 1.0000x reference)
//
#include <hip/hip_runtime.h>
#include <hip/hip_bf16.h>

// Grouped GEMM: out[e] = x[e] @ w[e]^T
//   x: [E=16, M=256, K=2048] fp32
//   w: [E=16, N=8192, K=2048] fp32 (K-major, MFMA-friendly)
//   out: [E, M, N] fp32
//
// HBM-bound problem (min traffic 1.24 GB -> ~197us floor). Strategy:
//   BM=256 (=M): W fetched exactly once (1.07 GB irreducible).
//   BN=128, BK=64, 512 threads / 8 waves (2Mx4N, 128x32 per wave).
//   Double-buffered XOR-swizzled bf16 LDS; reg-staged fp32->bf16 convert.
//   Single barrier per K-tile; next-tile loads issued BEFORE current MFMA
//   so HBM never drains (T14 async-stage split).

typedef __bf16 bf16_t;
typedef float f32x4 __attribute__((ext_vector_type(4)));
typedef bf16_t bf16x8 __attribute__((ext_vector_type(8)));

#define E_ 16
#define M_ 256
#define K_ 2048
#define N_ 8192
#define BM 256
#define BN 128
#define BK 64
#define NT (K_ / BK)   // 32 K-tiles
#define THREADS 512

// Element offset of an 8-element (16 B) chunk in a [rows][BK] bf16 tile,
// with the 16B-slot index XOR-swizzled by the row (kills the 16-way
// bank conflict a 128 B row stride would cause on ds_read_b128).
__device__ __forceinline__ int swz(int row, int c8) {
    return row * BK + (((c8 ^ row) & 7) << 3);
}

__global__ __launch_bounds__(THREADS, 2) void grouped_gemm_bf16mfma(
    const float* __restrict__ X, const float* __restrict__ W,
    float* __restrict__ O)
{
    const int bn = blockIdx.x;   // 0..63  (N tiles)
    const int e  = blockIdx.y;   // 0..15  (expert)

    const float* A = X + (size_t)e * M_ * K_;                        // full M per block
    const float* B = W + (size_t)e * N_ * K_ + (size_t)bn * BN * K_;
    float*       C = O + (size_t)e * M_ * N_ + (size_t)bn * BN;

    __shared__ bf16_t Asb[2][BM * BK];   // 2 x 32 KB
    __shared__ bf16_t Bsb[2][BN * BK];   // 2 x 16 KB   (96 KB total)

    const int tid  = threadIdx.x;
    const int lane = tid & 63;
    const int wave = tid >> 6;          // 0..7
    const int wm   = (wave >> 2) * 128; // wave M offset (2 waves in M)
    const int wn   = (wave & 3) * 32;   // wave N offset (4 waves in N)

    // MFMA 16x16x32 fragment addressing: lane = fr + 16*kg
    const int fr = lane & 15;
    const int kg = lane >> 4;           // 0..3 (8-elem k-group)

    // staging: each thread owns 16B chunks (8 fp32 -> 8 bf16)
    //   A: rows p*64+srow (p=0..3), chunk sch   B: rows p*64+srow (p=0..1)
    const int srow = tid >> 3;          // 0..63
    const int sch  = tid & 7;           // chunk 0..7 within a BK=64 row

    f32x4 acc[8][2];
#pragma unroll
    for (int i = 0; i < 8; ++i)
#pragma unroll
        for (int j = 0; j < 2; ++j)
            acc[i][j] = (f32x4){0.f, 0.f, 0.f, 0.f};

    f32x4 sa[4][2], sb[2][2];           // in-flight fp32 stage (48 VGPR)

    const float* ag = A + (size_t)srow * K_ + sch * 8;
    const float* bg = B + (size_t)srow * K_ + sch * 8;

    auto LOADT = [&](int t) {
        const int k0 = t * BK;
#pragma unroll
        for (int p = 0; p < 4; ++p) {
            const float* s = ag + (size_t)(p * 64) * K_ + k0;
            sa[p][0] = *(const f32x4*)(s);
            sa[p][1] = *(const f32x4*)(s + 4);
        }
#pragma unroll
        for (int p = 0; p < 2; ++p) {
            const float* s = bg + (size_t)(p * 64) * K_ + k0;
            sb[p][0] = *(const f32x4*)(s);
            sb[p][1] = *(const f32x4*)(s + 4);
        }
    };

    auto STORET = [&](int buf) {
#pragma unroll
        for (int p = 0; p < 4; ++p) {
            bf16x8 v;
#pragma unroll
            for (int q = 0; q < 4; ++q) {
                v[q]     = (bf16_t)sa[p][0][q];
                v[4 + q] = (bf16_t)sa[p][1][q];
            }
            *(bf16x8*)&Asb[buf][swz(p * 64 + srow, sch)] = v;
        }
#pragma unroll
        for (int p = 0; p < 2; ++p) {
            bf16x8 v;
#pragma unroll
            for (int q = 0; q < 4; ++q) {
                v[q]     = (bf16_t)sb[p][0][q];
                v[4 + q] = (bf16_t)sb[p][1][q];
            }
            *(bf16x8*)&Bsb[buf][swz(p * 64 + srow, sch)] = v;
        }
    };

    // prologue: stage tile 0 into buf 0
    LOADT(0);
    STORET(0);

    for (int t = 0; t < NT; ++t) {
        // One barrier per tile: makes buf[t&1] writes visible AND guarantees
        // everyone finished reading buf[(t+1)&1] last iteration, so this
        // iteration may overwrite it without a second barrier.
        __syncthreads();

        // issue next tile's global loads first -> in flight under the MFMAs
        if (t + 1 < NT) LOADT(t + 1);

        const int rb = t & 1;
#pragma unroll
        for (int ks = 0; ks < 2; ++ks) {
            bf16x8 bv[2];
#pragma unroll
            for (int j = 0; j < 2; ++j)
                bv[j] = *(const bf16x8*)&Bsb[rb][swz(wn + j * 16 + fr, ks * 4 + kg)];
#pragma unroll
            for (int i = 0; i < 8; ++i) {
                bf16x8 av = *(const bf16x8*)&Asb[rb][swz(wm + i * 16 + fr, ks * 4 + kg)];
#pragma unroll
                for (int j = 0; j < 2; ++j)
                    acc[i][j] = __builtin_amdgcn_mfma_f32_16x16x32_bf16(
                        av, bv[j], acc[i][j], 0, 0, 0);
            }
        }

        // convert + write next tile into the other buffer (vmcnt wait here,
        // fully overlapped with the MFMA block above)
        if (t + 1 < NT) STORET(rb ^ 1);
    }

    // epilogue: C/D layout col = lane&15, row = (lane>>4)*4 + reg
#pragma unroll
    for (int i = 0; i < 8; ++i) {
        const int orow = wm + i * 16 + kg * 4;
#pragma unroll
        for (int j = 0; j < 2; ++j) {
            const int ocol = wn + j * 16 + fr;
#pragma unroll
            for (int r = 0; r < 4; ++r)
                C[(size_t)(orow + r) * N_ + ocol] = acc[i][j][r];
        }
    }
}

extern "C" void kernel_launch(void* const* d_in, const int* in_sizes, int n_in,
                              void* d_out, int out_size, void* d_ws, size_t ws_size,
                              hipStream_t stream) {
    const float* X = (const float*)d_in[0];
    const float* W = (const float*)d_in[1];
    float* O = (float*)d_out;
    dim3 grid(N_ / BN, E_);   // (64, 16) = 1024 blocks, 1 per CU, 4 generations
    dim3 block(THREADS);
    grouped_gemm_bf16mfma<<<grid, block, 0, stream>>>(X, W, O);
}